// Round 6
// baseline (388.372 us; speedup 1.0000x reference)
//
#include <hip/hip_runtime.h>

typedef float f2 __attribute__((ext_vector_type(2)));

// Problem constants (fixed by setup_inputs: B=8, N=M=8192, D=3, fp32).
constexpr int BATCH  = 8;
constexpr int NPTS   = 8192;          // N == M
constexpr int TCHUNK = 256;           // database points staged in LDS per block
constexpr int NSPLIT = NPTS / TCHUNK; // 32 database chunks (grid.z)
constexpr int BLOCK  = 256;
constexpr int IPT    = 8;             // queries per thread
constexpr int NPK    = IPT / 2;       // query float2-pairs per thread
constexpr int QPB    = BLOCK * IPT;   // 2048 queries per block
constexpr int QBLKS  = NPTS / QPB;    // 4 query blocks per direction
constexpr unsigned TOTAL_BLOCKS = 2 * QBLKS * BATCH * NSPLIT;  // 2048
constexpr unsigned TICKET_INIT  = 0x7f7f7f7fu;  // memset(0x7f) pattern

static __device__ __forceinline__ f2 fma2(f2 a, f2 b, f2 c) {
    return __builtin_elementwise_fma(a, b, c);
}
static __device__ __forceinline__ f2 min2(f2 a, f2 b) {
    return __builtin_elementwise_min(a, b);
}

// min_t |q-t|^2 = |q|^2 + 2*min_t(0.5|t|^2 - q.t). Queries packed in float2
// pairs -> inner body per point per pair-pack: 3 v_pk_fma_f32 + 2 v_min_f32
// (2.5 instr-slots per (query,point) pair). Chunk partials combine via
// atomicMin on float bits; the last block (device-scope ticket) reduces the
// 512 KB mins buffer to out[0..7]. ws use: 512 KB + 4 B (R1/R5-proven size).
__global__ __launch_bounds__(BLOCK, 8) void chamfer_nn_kernel(
    const float* __restrict__ src, const float* __restrict__ tgt,
    unsigned int* __restrict__ mins,   // [2][BATCH][NPTS] float-as-uint, +1 ticket
    float* __restrict__ out)
{
    __shared__ float4 sh[TCHUNK];

    const int dir   = blockIdx.x / QBLKS;  // 0: queries=src, db=tgt ; 1: swapped
    const int xblk  = blockIdx.x % QBLKS;
    const int b     = blockIdx.y;
    const int chunk = blockIdx.z;

    const float* __restrict__ P = dir ? tgt : src;  // query points
    const float* __restrict__ Q = dir ? src : tgt;  // database points

    // --- stage database chunk into LDS as (x, y, z, 0.5*|p|^2) ---
    {
        const float* dbase = Q + ((size_t)b * NPTS + (size_t)chunk * TCHUNK) * 3;
        const int j = threadIdx.x;  // BLOCK == TCHUNK
        float x = dbase[3 * j + 0];
        float y = dbase[3 * j + 1];
        float z = dbase[3 * j + 2];
        sh[j] = make_float4(x, y, z, 0.5f * fmaf(x, x, fmaf(y, y, z * z)));
    }

    // --- load my IPT query points as float2 packs (negated coords) ---
    f2 qnx[NPK], qny[NPK], qnz[NPK], mn[NPK];
    const int q0 = xblk * QPB + (int)threadIdx.x;
    const float* pbase = P + (size_t)b * NPTS * 3;
#pragma unroll
    for (int p = 0; p < NPK; p++) {
        const float* pa = pbase + (size_t)(q0 + (2 * p + 0) * BLOCK) * 3;
        const float* pb = pbase + (size_t)(q0 + (2 * p + 1) * BLOCK) * 3;
        qnx[p] = f2{-pa[0], -pb[0]};
        qny[p] = f2{-pa[1], -pb[1]};
        qnz[p] = f2{-pa[2], -pb[2]};
        mn[p]  = f2{3.4e38f, 3.4e38f};
    }
    __syncthreads();

    // --- main loop: 3 pk_fma + 2 min per (point, query-pair) ---
#pragma unroll 4
    for (int j = 0; j < TCHUNK; j++) {
        float4 t = sh[j];
        f2 tx = f2{t.x, t.x};
        f2 ty = f2{t.y, t.y};
        f2 tz = f2{t.z, t.z};
        f2 tw = f2{t.w, t.w};
#pragma unroll
        for (int p = 0; p < NPK; p++) {
            f2 v = fma2(qnx[p], tx, fma2(qny[p], ty, fma2(qnz[p], tz, tw)));
            mn[p] = min2(mn[p], v);
        }
    }

    // --- epilogue: d = max(|q|^2 + 2*v_min, 0); combine via atomicMin ---
    unsigned int* mout = mins + ((size_t)dir * BATCH + b) * NPTS;
#pragma unroll
    for (int p = 0; p < NPK; p++) {
#pragma unroll
        for (int h = 0; h < 2; h++) {
            float nx = qnx[p][h], ny = qny[p][h], nz = qnz[p][h];
            float qs = fmaf(nx, nx, fmaf(ny, ny, nz * nz));
            float d  = fmaxf(fmaf(2.0f, mn[p][h], qs), 0.0f);
            atomicMin(&mout[q0 + (2 * p + h) * BLOCK], __float_as_uint(d));
        }
    }

    // --- last-block final reduction (device-scope ticket) ---
    __threadfence();  // release my atomicMin results
    __shared__ bool amLast;
    if (threadIdx.x == 0) {
        unsigned int old = atomicAdd(&mins[2 * BATCH * NPTS], 1u);
        amLast = (old == TICKET_INIT + (TOTAL_BLOCKS - 1));
    }
    __syncthreads();
    if (!amLast) return;
    __threadfence();  // acquire everyone else's atomicMin results

    __shared__ float wsum[BLOCK / 64];
    const int lane = threadIdx.x & 63;
    const int wid  = threadIdx.x >> 6;
    for (int bb = 0; bb < BATCH; bb++) {
        float acc = 0.0f;
        for (int d2 = 0; d2 < 2; d2++) {
            const unsigned int* pm = mins + ((size_t)d2 * BATCH + bb) * NPTS;
            for (int q = threadIdx.x; q < NPTS; q += BLOCK)
                acc += __uint_as_float(pm[q]);
        }
        for (int off = 32; off > 0; off >>= 1) acc += __shfl_down(acc, off, 64);
        if (lane == 0) wsum[wid] = acc;
        __syncthreads();
        if (threadIdx.x == 0)
            out[bb] = (wsum[0] + wsum[1] + wsum[2] + wsum[3]) * (1.0f / (float)NPTS);
        __syncthreads();
    }
}

extern "C" void kernel_launch(void* const* d_in, const int* in_sizes, int n_in,
                              void* d_out, int out_size, void* d_ws, size_t ws_size,
                              hipStream_t stream) {
    const float* src = (const float*)d_in[0];  // [B, N, 3]
    const float* tgt = (const float*)d_in[1];  // [B, M, 3]
    float* out = (float*)d_out;                // [B]

    unsigned int* mins = (unsigned int*)d_ws;  // [2][B][NPTS] + 1 ticket
    const size_t init_bytes = ((size_t)2 * BATCH * NPTS + 1) * sizeof(unsigned int);

    // 0x7f7f7f7f ~= 3.39e38 (mins sentinel) and the ticket's start value.
    // ws is re-poisoned before every timed call, so this must run each launch.
    hipMemsetAsync(d_ws, 0x7f, init_bytes, stream);

    dim3 grid(2 * QBLKS, BATCH, NSPLIT);  // 8 x 8 x 32 = 2048 blocks
    chamfer_nn_kernel<<<grid, BLOCK, 0, stream>>>(src, tgt, mins, out);
}

// Round 7
// 320.239 us; speedup vs baseline: 1.2128x; 1.2128x over previous
//
#include <hip/hip_runtime.h>

typedef float f2 __attribute__((ext_vector_type(2)));

// Problem constants (fixed by setup_inputs: B=8, N=M=8192, D=3, fp32).
constexpr int BATCH  = 8;
constexpr int NPTS   = 8192;          // N == M
constexpr int TCHUNK = 256;           // database points staged in LDS per block
constexpr int NSPLIT = NPTS / TCHUNK; // 32 database chunks (grid.z)
constexpr int BLOCK  = 256;
constexpr int IPT    = 8;             // queries per thread
constexpr int NPK    = IPT / 2;       // query float2-pairs per thread
constexpr int QPB    = BLOCK * IPT;   // 2048 queries per block
constexpr int QBLKS  = NPTS / QPB;    // 4 query blocks per direction
constexpr unsigned TOTAL_BLOCKS = 2 * QBLKS * BATCH * NSPLIT;  // 2048
constexpr unsigned TICKET_INIT  = 0x7f7f7f7fu;  // memset(0x7f) pattern

static __device__ __forceinline__ f2 fma2(f2 a, f2 b, f2 c) {
    return __builtin_elementwise_fma(a, b, c);
}
static __device__ __forceinline__ f2 min2(f2 a, f2 b) {
    return __builtin_elementwise_min(a, b);
}

// min_t |q-t|^2 = |q|^2 + 2*min_t(0.5|t|^2 - q.t). Queries packed in float2
// pairs -> inner body per point per pair-pack: 3 v_pk_fma_f32 + mins.
// R6 post-mortem: __launch_bounds__(256,8) capped VGPR at 32 and spilled the
// f2 state to scratch (59 MB spill writes, VALUBusy 18%). No min-waves arg:
// ~56 VGPR <= 64 still gives 8 blocks/CU without spilling.
__global__ __launch_bounds__(BLOCK) void chamfer_nn_kernel(
    const float* __restrict__ src, const float* __restrict__ tgt,
    unsigned int* __restrict__ mins,   // [2][BATCH][NPTS] float-as-uint, +1 ticket
    float* __restrict__ out)
{
    __shared__ float4 sh[TCHUNK];

    const int dir   = blockIdx.x / QBLKS;  // 0: queries=src, db=tgt ; 1: swapped
    const int xblk  = blockIdx.x % QBLKS;
    const int b     = blockIdx.y;
    const int chunk = blockIdx.z;

    const float* __restrict__ P = dir ? tgt : src;  // query points
    const float* __restrict__ Q = dir ? src : tgt;  // database points

    // --- stage database chunk into LDS as (x, y, z, 0.5*|p|^2) ---
    {
        const float* dbase = Q + ((size_t)b * NPTS + (size_t)chunk * TCHUNK) * 3;
        const int j = threadIdx.x;  // BLOCK == TCHUNK
        float x = dbase[3 * j + 0];
        float y = dbase[3 * j + 1];
        float z = dbase[3 * j + 2];
        sh[j] = make_float4(x, y, z, 0.5f * fmaf(x, x, fmaf(y, y, z * z)));
    }

    // --- load my IPT query points as float2 packs (negated coords) ---
    f2 qnx[NPK], qny[NPK], qnz[NPK], mn[NPK];
    const int q0 = xblk * QPB + (int)threadIdx.x;
    const float* pbase = P + (size_t)b * NPTS * 3;
#pragma unroll
    for (int p = 0; p < NPK; p++) {
        const float* pa = pbase + (size_t)(q0 + (2 * p + 0) * BLOCK) * 3;
        const float* pb = pbase + (size_t)(q0 + (2 * p + 1) * BLOCK) * 3;
        qnx[p] = f2{-pa[0], -pb[0]};
        qny[p] = f2{-pa[1], -pb[1]};
        qnz[p] = f2{-pa[2], -pb[2]};
        mn[p]  = f2{3.4e38f, 3.4e38f};
    }
    __syncthreads();

    // --- main loop: 3 pk_fma + packed min per (point, query-pair) ---
#pragma unroll 4
    for (int j = 0; j < TCHUNK; j++) {
        float4 t = sh[j];
        f2 tx = f2{t.x, t.x};
        f2 ty = f2{t.y, t.y};
        f2 tz = f2{t.z, t.z};
        f2 tw = f2{t.w, t.w};
#pragma unroll
        for (int p = 0; p < NPK; p++) {
            f2 v = fma2(qnx[p], tx, fma2(qny[p], ty, fma2(qnz[p], tz, tw)));
            mn[p] = min2(mn[p], v);
        }
    }

    // --- epilogue: d = max(|q|^2 + 2*v_min, 0); combine via atomicMin ---
    unsigned int* mout = mins + ((size_t)dir * BATCH + b) * NPTS;
#pragma unroll
    for (int p = 0; p < NPK; p++) {
#pragma unroll
        for (int h = 0; h < 2; h++) {
            float nx = qnx[p][h], ny = qny[p][h], nz = qnz[p][h];
            float qs = fmaf(nx, nx, fmaf(ny, ny, nz * nz));
            float d  = fmaxf(fmaf(2.0f, mn[p][h], qs), 0.0f);
            atomicMin(&mout[q0 + (2 * p + h) * BLOCK], __float_as_uint(d));
        }
    }

    // --- last-block final reduction (device-scope ticket) ---
    __threadfence();  // release my atomicMin results
    __shared__ bool amLast;
    if (threadIdx.x == 0) {
        unsigned int old = atomicAdd(&mins[2 * BATCH * NPTS], 1u);
        amLast = (old == TICKET_INIT + (TOTAL_BLOCKS - 1));
    }
    __syncthreads();
    if (!amLast) return;
    __threadfence();  // acquire everyone else's atomicMin results

    __shared__ float wsum[BLOCK / 64];
    const int lane = threadIdx.x & 63;
    const int wid  = threadIdx.x >> 6;
    for (int bb = 0; bb < BATCH; bb++) {
        float acc = 0.0f;
        for (int d2 = 0; d2 < 2; d2++) {
            const unsigned int* pm = mins + ((size_t)d2 * BATCH + bb) * NPTS;
            for (int q = threadIdx.x; q < NPTS; q += BLOCK)
                acc += __uint_as_float(pm[q]);
        }
        for (int off = 32; off > 0; off >>= 1) acc += __shfl_down(acc, off, 64);
        if (lane == 0) wsum[wid] = acc;
        __syncthreads();
        if (threadIdx.x == 0)
            out[bb] = (wsum[0] + wsum[1] + wsum[2] + wsum[3]) * (1.0f / (float)NPTS);
        __syncthreads();
    }
}

extern "C" void kernel_launch(void* const* d_in, const int* in_sizes, int n_in,
                              void* d_out, int out_size, void* d_ws, size_t ws_size,
                              hipStream_t stream) {
    const float* src = (const float*)d_in[0];  // [B, N, 3]
    const float* tgt = (const float*)d_in[1];  // [B, M, 3]
    float* out = (float*)d_out;                // [B]

    unsigned int* mins = (unsigned int*)d_ws;  // [2][B][NPTS] + 1 ticket
    const size_t init_bytes = ((size_t)2 * BATCH * NPTS + 1) * sizeof(unsigned int);

    // 0x7f7f7f7f ~= 3.39e38 (mins sentinel) and the ticket's start value.
    // ws is re-poisoned before every timed call, so this must run each launch.
    hipMemsetAsync(d_ws, 0x7f, init_bytes, stream);

    dim3 grid(2 * QBLKS, BATCH, NSPLIT);  // 8 x 8 x 32 = 2048 blocks
    chamfer_nn_kernel<<<grid, BLOCK, 0, stream>>>(src, tgt, mins, out);
}

// Round 9
// 135.758 us; speedup vs baseline: 2.8608x; 2.3589x over previous
//
#include <hip/hip_runtime.h>

typedef float f2 __attribute__((ext_vector_type(2)));

// Problem constants (fixed by setup_inputs: B=8, N=M=8192, D=3, fp32).
constexpr int BATCH  = 8;
constexpr int NPTS   = 8192;          // N == M
constexpr int TCHUNK = 256;           // database points staged in LDS per block
constexpr int NSPLIT = NPTS / TCHUNK; // 32 database chunks (grid.z)
constexpr int BLOCK  = 256;
constexpr int IPT    = 8;             // queries per thread
constexpr int NPK    = IPT / 2;       // query float2-pairs per thread
constexpr int QPB    = BLOCK * IPT;   // 2048 queries per block
constexpr int QBLKS  = NPTS / QPB;    // 4 query blocks per direction

static __device__ __forceinline__ f2 fma2(f2 a, f2 b, f2 c) {
    return __builtin_elementwise_fma(a, b, c);
}
static __device__ __forceinline__ f2 min2(f2 a, f2 b) {
    return __builtin_elementwise_min(a, b);
}

// min_t |q-t|^2 = |q|^2 + 2*min_t(0.5|t|^2 - q.t). Queries packed in float2
// pairs -> 3 v_pk_fma_f32 + 1 pk-min per (point, query-pair) = 2 instr-slots
// per (query,point) pair (R6/R7 evidence: VALU busy time 106us scalar -> 60us
// packed). R8 post-mortem: single-kernel fusion chased a FIXED ~45us harness
// overhead (same at 1-3 dispatches) and its cross-block handoff is the prime
// suspect for two container deaths -> back to the container-proven R5
// two-kernel structure. No __threadfence (R7: ~200us of per-block L2
// writeback); inter-kernel visibility comes from stream ordering.
// No min-waves launch_bounds arg (R6: VGPR cap 32 -> scratch spill disaster).
__global__ __launch_bounds__(BLOCK) void chamfer_nn_kernel(
    const float* __restrict__ src, const float* __restrict__ tgt,
    unsigned int* __restrict__ mins)   // [2][BATCH][NPTS] float-as-uint
{
    __shared__ float4 sh[TCHUNK];

    const int dir   = blockIdx.x / QBLKS;  // 0: queries=src, db=tgt ; 1: swapped
    const int xblk  = blockIdx.x % QBLKS;
    const int b     = blockIdx.y;
    const int chunk = blockIdx.z;

    const float* __restrict__ P = dir ? tgt : src;  // query points
    const float* __restrict__ Q = dir ? src : tgt;  // database points

    // --- stage database chunk into LDS as (x, y, z, 0.5*|p|^2) ---
    {
        const float* dbase = Q + ((size_t)b * NPTS + (size_t)chunk * TCHUNK) * 3;
        const int j = threadIdx.x;  // BLOCK == TCHUNK
        float x = dbase[3 * j + 0];
        float y = dbase[3 * j + 1];
        float z = dbase[3 * j + 2];
        sh[j] = make_float4(x, y, z, 0.5f * fmaf(x, x, fmaf(y, y, z * z)));
    }

    // --- load my IPT query points as float2 packs (negated coords) ---
    f2 qnx[NPK], qny[NPK], qnz[NPK], mn[NPK];
    const int q0 = xblk * QPB + (int)threadIdx.x;
    const float* pbase = P + (size_t)b * NPTS * 3;
#pragma unroll
    for (int p = 0; p < NPK; p++) {
        const float* pa = pbase + (size_t)(q0 + (2 * p + 0) * BLOCK) * 3;
        const float* pb = pbase + (size_t)(q0 + (2 * p + 1) * BLOCK) * 3;
        qnx[p] = f2{-pa[0], -pb[0]};
        qny[p] = f2{-pa[1], -pb[1]};
        qnz[p] = f2{-pa[2], -pb[2]};
        mn[p]  = f2{3.4e38f, 3.4e38f};
    }
    __syncthreads();

    // --- main loop: 3 pk_fma + 1 pk-min per (point, query-pair) ---
#pragma unroll 4
    for (int j = 0; j < TCHUNK; j++) {
        float4 t = sh[j];
        f2 tx = f2{t.x, t.x};
        f2 ty = f2{t.y, t.y};
        f2 tz = f2{t.z, t.z};
        f2 tw = f2{t.w, t.w};
#pragma unroll
        for (int p = 0; p < NPK; p++) {
            f2 v = fma2(qnx[p], tx, fma2(qny[p], ty, fma2(qnz[p], tz, tw)));
            mn[p] = min2(mn[p], v);
        }
    }

    // --- epilogue: d = max(|q|^2 + 2*v_min, 0); combine via atomicMin ---
    unsigned int* mout = mins + ((size_t)dir * BATCH + b) * NPTS;
#pragma unroll
    for (int p = 0; p < NPK; p++) {
#pragma unroll
        for (int h = 0; h < 2; h++) {
            float nx = qnx[p][h], ny = qny[p][h], nz = qnz[p][h];
            float qs = fmaf(nx, nx, fmaf(ny, ny, nz * nz));
            float d  = fmaxf(fmaf(2.0f, mn[p][h], qs), 0.0f);
            atomicMin(&mout[q0 + (2 * p + h) * BLOCK], __float_as_uint(d));
        }
    }
}

// One block per batch (1024 threads): sum final mins for both directions.
// Only 512 KB total input, L2-resident. Deterministic, no atomics, no fences
// (stream ordering makes kernel-1 results visible — R5-proven).
__global__ __launch_bounds__(1024) void chamfer_out_kernel(
    const unsigned int* __restrict__ mins, float* __restrict__ out)
{
    const int b = blockIdx.x;
    float acc = 0.0f;
    for (int dir = 0; dir < 2; dir++) {
        const unsigned int* p = mins + ((size_t)dir * BATCH + b) * NPTS;
        for (int q = threadIdx.x; q < NPTS; q += 1024)
            acc += __uint_as_float(p[q]);
    }
    // wave (64-lane) shuffle reduction, then cross-wave via LDS
    for (int off = 32; off > 0; off >>= 1) acc += __shfl_down(acc, off, 64);
    __shared__ float wsum[16];
    const int lane = threadIdx.x & 63;
    const int wid  = threadIdx.x >> 6;
    if (lane == 0) wsum[wid] = acc;
    __syncthreads();
    if (threadIdx.x < 64) {
        float s = (threadIdx.x < 16) ? wsum[threadIdx.x] : 0.0f;
        for (int off = 8; off > 0; off >>= 1) s += __shfl_down(s, off, 64);
        if (threadIdx.x == 0) out[b] = s * (1.0f / (float)NPTS);
    }
}

extern "C" void kernel_launch(void* const* d_in, const int* in_sizes, int n_in,
                              void* d_out, int out_size, void* d_ws, size_t ws_size,
                              hipStream_t stream) {
    const float* src = (const float*)d_in[0];  // [B, N, 3]
    const float* tgt = (const float*)d_in[1];  // [B, M, 3]
    float* out = (float*)d_out;                // [B]

    unsigned int* mins = (unsigned int*)d_ws;  // [2][B][NPTS] = 512 KB
    const size_t min_bytes = (size_t)2 * BATCH * NPTS * sizeof(unsigned int);

    // Init mins to a huge positive float (0x7f7f7f7f ~= 3.39e38). Workspace is
    // re-poisoned before every timed call, so this must run every launch.
    hipMemsetAsync(d_ws, 0x7f, min_bytes, stream);

    dim3 grid(2 * QBLKS, BATCH, NSPLIT);  // 8 x 8 x 32 = 2048 blocks
    chamfer_nn_kernel<<<grid, BLOCK, 0, stream>>>(src, tgt, mins);

    chamfer_out_kernel<<<BATCH, 1024, 0, stream>>>(mins, out);
}

// Round 10
// 134.551 us; speedup vs baseline: 2.8864x; 1.0090x over previous
//
#include <hip/hip_runtime.h>

typedef float f2 __attribute__((ext_vector_type(2)));

// Problem constants (fixed by setup_inputs: B=8, N=M=8192, D=3, fp32).
constexpr int BATCH  = 8;
constexpr int NPTS   = 8192;          // N == M
constexpr int TCHUNK = 256;           // database points staged in LDS per block
constexpr int NSPLIT = NPTS / TCHUNK; // 32 database chunks (grid.z)
constexpr int BLOCK  = 256;
constexpr int IPT    = 16;            // queries per thread (R10: 8->16)
constexpr int NPK    = IPT / 2;       // query float2-pairs per thread
constexpr int QPB    = BLOCK * IPT;   // 4096 queries per block
constexpr int QBLKS  = NPTS / QPB;    // 2 query blocks per direction

static __device__ __forceinline__ f2 fma2(f2 a, f2 b, f2 c) {
    return __builtin_elementwise_fma(a, b, c);
}
static __device__ __forceinline__ f2 min2(f2 a, f2 b) {
    return __builtin_elementwise_min(a, b);
}

// min_t |q-t|^2 = |q|^2 + 2*min_t(0.5|t|^2 - q.t), queries in float2 packs
// (3 v_pk_fma_f32 + 1 pk-min per point per pack).
// R9 post-mortem: wall 83us == DS-pipe model (32 waves x 256 ds_read_b128
// broadcasts x ~24cyc = 82us/CU), invariant to VALU halving -> LDS-read-bound.
// Fix: IPT=16 halves DS reads per (query,point) pair. 1024 blocks = 4/CU
// resident (VGPR ~90 -> 4 waves/SIMD): DS ~41us, VALU ~34us.
// No min-waves launch_bounds (R6: cap->spill). No __threadfence (R7: ~200us).
__global__ __launch_bounds__(BLOCK) void chamfer_nn_kernel(
    const float* __restrict__ src, const float* __restrict__ tgt,
    unsigned int* __restrict__ mins)   // [2][BATCH][NPTS] float-as-uint
{
    __shared__ float4 sh[TCHUNK];

    const int dir   = blockIdx.x / QBLKS;  // 0: queries=src, db=tgt ; 1: swapped
    const int xblk  = blockIdx.x % QBLKS;
    const int b     = blockIdx.y;
    const int chunk = blockIdx.z;

    const float* __restrict__ P = dir ? tgt : src;  // query points
    const float* __restrict__ Q = dir ? src : tgt;  // database points

    // --- stage database chunk into LDS as (x, y, z, 0.5*|p|^2) ---
    {
        const float* dbase = Q + ((size_t)b * NPTS + (size_t)chunk * TCHUNK) * 3;
        const int j = threadIdx.x;  // BLOCK == TCHUNK
        float x = dbase[3 * j + 0];
        float y = dbase[3 * j + 1];
        float z = dbase[3 * j + 2];
        sh[j] = make_float4(x, y, z, 0.5f * fmaf(x, x, fmaf(y, y, z * z)));
    }

    // --- load my IPT query points as float2 packs (negated coords) ---
    f2 qnx[NPK], qny[NPK], qnz[NPK], mn[NPK];
    const int q0 = xblk * QPB + (int)threadIdx.x;
    const float* pbase = P + (size_t)b * NPTS * 3;
#pragma unroll
    for (int p = 0; p < NPK; p++) {
        const float* pa = pbase + (size_t)(q0 + (2 * p + 0) * BLOCK) * 3;
        const float* pb = pbase + (size_t)(q0 + (2 * p + 1) * BLOCK) * 3;
        qnx[p] = f2{-pa[0], -pb[0]};
        qny[p] = f2{-pa[1], -pb[1]};
        qnz[p] = f2{-pa[2], -pb[2]};
        mn[p]  = f2{3.4e38f, 3.4e38f};
    }
    __syncthreads();

    // --- main loop: 1 ds_read_b128 + 8x(3 pk_fma + 1 pk_min) per point ---
#pragma unroll 2
    for (int j = 0; j < TCHUNK; j++) {
        float4 t = sh[j];
        f2 tx = f2{t.x, t.x};
        f2 ty = f2{t.y, t.y};
        f2 tz = f2{t.z, t.z};
        f2 tw = f2{t.w, t.w};
#pragma unroll
        for (int p = 0; p < NPK; p++) {
            f2 v = fma2(qnx[p], tx, fma2(qny[p], ty, fma2(qnz[p], tz, tw)));
            mn[p] = min2(mn[p], v);
        }
    }

    // --- epilogue: d = max(|q|^2 + 2*v_min, 0); combine via atomicMin ---
    unsigned int* mout = mins + ((size_t)dir * BATCH + b) * NPTS;
#pragma unroll
    for (int p = 0; p < NPK; p++) {
#pragma unroll
        for (int h = 0; h < 2; h++) {
            float nx = qnx[p][h], ny = qny[p][h], nz = qnz[p][h];
            float qs = fmaf(nx, nx, fmaf(ny, ny, nz * nz));
            float d  = fmaxf(fmaf(2.0f, mn[p][h], qs), 0.0f);
            atomicMin(&mout[q0 + (2 * p + h) * BLOCK], __float_as_uint(d));
        }
    }
}

// One block per batch (1024 threads): sum final mins for both directions.
// 512 KB total input, L2-resident. Stream ordering guarantees visibility.
__global__ __launch_bounds__(1024) void chamfer_out_kernel(
    const unsigned int* __restrict__ mins, float* __restrict__ out)
{
    const int b = blockIdx.x;
    float acc = 0.0f;
    for (int dir = 0; dir < 2; dir++) {
        const unsigned int* p = mins + ((size_t)dir * BATCH + b) * NPTS;
        for (int q = threadIdx.x; q < NPTS; q += 1024)
            acc += __uint_as_float(p[q]);
    }
    // wave (64-lane) shuffle reduction, then cross-wave via LDS
    for (int off = 32; off > 0; off >>= 1) acc += __shfl_down(acc, off, 64);
    __shared__ float wsum[16];
    const int lane = threadIdx.x & 63;
    const int wid  = threadIdx.x >> 6;
    if (lane == 0) wsum[wid] = acc;
    __syncthreads();
    if (threadIdx.x < 64) {
        float s = (threadIdx.x < 16) ? wsum[threadIdx.x] : 0.0f;
        for (int off = 8; off > 0; off >>= 1) s += __shfl_down(s, off, 64);
        if (threadIdx.x == 0) out[b] = s * (1.0f / (float)NPTS);
    }
}

extern "C" void kernel_launch(void* const* d_in, const int* in_sizes, int n_in,
                              void* d_out, int out_size, void* d_ws, size_t ws_size,
                              hipStream_t stream) {
    const float* src = (const float*)d_in[0];  // [B, N, 3]
    const float* tgt = (const float*)d_in[1];  // [B, M, 3]
    float* out = (float*)d_out;                // [B]

    unsigned int* mins = (unsigned int*)d_ws;  // [2][B][NPTS] = 512 KB
    const size_t min_bytes = (size_t)2 * BATCH * NPTS * sizeof(unsigned int);

    // Init mins to a huge positive float (0x7f7f7f7f ~= 3.39e38). Workspace is
    // re-poisoned before every timed call, so this must run every launch.
    hipMemsetAsync(d_ws, 0x7f, min_bytes, stream);

    dim3 grid(2 * QBLKS, BATCH, NSPLIT);  // 4 x 8 x 32 = 1024 blocks
    chamfer_nn_kernel<<<grid, BLOCK, 0, stream>>>(src, tgt, mins);

    chamfer_out_kernel<<<BATCH, 1024, 0, stream>>>(mins, out);
}